// Round 12
// baseline (425.334 us; speedup 1.0000x reference)
//
#include <hip/hip_runtime.h>
#include <hip/hip_bf16.h>
#include <math.h>

// Problem constants
constexpr int cB = 4, cT = 256, cS = 400, cD = 512, cV = 50000, cNX = 50;
constexpr int cVEXT = cV + cNX;           // 50050
constexpr int cPAN2 = (cV + 255) / 256;   // 196 col panels (256-wide) of big GEMM
constexpr int cCBLD = cVEXT * 2;          // ushort stride of one fp32 out row
constexpr int cTOP  = 50100;              // ushort offset of bf16 logits in-slot
constexpr int cMQ   = cB * cT;            // 1024

typedef __attribute__((ext_vector_type(8))) short short8v;   // 8 bf16
typedef __attribute__((ext_vector_type(4))) float floatx4;

__device__ inline ushort f2bf(float f) {
    union { float f; unsigned u; } v; v.f = f;
    unsigned r = (v.u + 0x7FFFu + ((v.u >> 16) & 1u)) >> 16;
    return (ushort)r;
}
__device__ inline float bf2f(ushort u) {
    union { unsigned u; float f; } v; v.u = ((unsigned)u) << 16;
    return v.f;
}

// ---------------------------------------------------------------------------
// fp32 -> bf16 cast
// ---------------------------------------------------------------------------
__global__ __launch_bounds__(256) void cast_kernel(
    const float* __restrict__ src, ushort* __restrict__ dst, int n4)
{
    const int stride = gridDim.x * 256;
    for (int i = blockIdx.x * 256 + threadIdx.x; i < n4; i += stride) {
        float4 v = *(const float4*)(src + (size_t)i * 4);
        ushort4 o;
        o.x = f2bf(v.x); o.y = f2bf(v.y); o.z = f2bf(v.z); o.w = f2bf(v.w);
        *(ushort4*)(dst + (size_t)i * 4) = o;
    }
}

// ---------------------------------------------------------------------------
// Small bf16 MFMA GEMM (projections): 128x128 tile, BK=32, 4 waves, frag-order
// LDS (0 bank conflicts), fp32 C + bias. Plain block mapping. (r11-proven.)
// ---------------------------------------------------------------------------
__global__ __launch_bounds__(256) void gemm_proj(
    const ushort* __restrict__ A, const ushort* __restrict__ Wb,
    const float* __restrict__ bias, float* __restrict__ Cf,
    int M, int N, int K, int ldc)
{
    __shared__ ushort As[2][128 * 32];
    __shared__ ushort Bs[2][128 * 32];

    const int tid  = threadIdx.x;
    const int lane = tid & 63;
    const int wv   = tid >> 6;
    const int wm   = wv >> 1;
    const int wn   = wv & 1;
    const int bm   = blockIdx.x * 128;
    const int bn   = blockIdx.y * 128;

    const int rA = lane & 15;
    const int kA = (lane >> 4) * 8;
    const int nt = K >> 5;

    floatx4 acc[4][4] = {};

    auto stage = [&](int bidx, int t) {
        const int k0 = t * 32;
        #pragma unroll
        for (int c = 0; c < 2; ++c) {
            const int chunk = wv * 2 + c;
            int ga = bm + chunk * 16 + rA; if (ga >= M) ga = M - 1;
            __builtin_amdgcn_global_load_lds(
                (const __attribute__((address_space(1))) void*)(A + (size_t)ga * K + k0 + kA),
                (__attribute__((address_space(3))) void*)&As[bidx][chunk * 512], 16, 0, 0);
            int gb = bn + chunk * 16 + rA; if (gb >= N) gb = N - 1;
            __builtin_amdgcn_global_load_lds(
                (const __attribute__((address_space(1))) void*)(Wb + (size_t)gb * K + k0 + kA),
                (__attribute__((address_space(3))) void*)&Bs[bidx][chunk * 512], 16, 0, 0);
        }
    };

    stage(0, 0);
    __syncthreads();

    int buf = 0;
    for (int t = 0; t < nt; ++t) {
        if (t + 1 < nt) stage(buf ^ 1, t + 1);
        short8v a[4], b[4];
        #pragma unroll
        for (int mi = 0; mi < 4; ++mi)
            a[mi] = *(const short8v*)&As[buf][(wm * 4 + mi) * 512 + lane * 8];
        #pragma unroll
        for (int ni = 0; ni < 4; ++ni)
            b[ni] = *(const short8v*)&Bs[buf][(wn * 4 + ni) * 512 + lane * 8];
        #pragma unroll
        for (int mi = 0; mi < 4; ++mi)
            #pragma unroll
            for (int ni = 0; ni < 4; ++ni)
                acc[mi][ni] = __builtin_amdgcn_mfma_f32_16x16x32_bf16(
                    a[mi], b[ni], acc[mi][ni], 0, 0, 0);
        __syncthreads();
        buf ^= 1;
    }

    const int fr = lane & 15;
    const int g  = lane >> 4;
    #pragma unroll
    for (int mi = 0; mi < 4; ++mi) {
        #pragma unroll
        for (int ni = 0; ni < 4; ++ni) {
            const int colg = bn + wn * 64 + ni * 16 + fr;
            if (colg >= N) continue;
            const float bv = bias[colg];
            #pragma unroll
            for (int r = 0; r < 4; ++r) {
                const int row = bm + wm * 64 + mi * 16 + g * 4 + r;
                if (row < M) Cf[(size_t)row * ldc + colg] = acc[mi][ni][r] + bv;
            }
        }
    }
}

// ---------------------------------------------------------------------------
// Big logits GEMM: 128x256 tile, BK=32, 512 thr = 8 waves (2m x 4n).
// COUNTED-VMCNT 2-DEEP PIPELINE (T4): loads for step t+2 are issued as step t
// ends and consumed at t+2 -- two full steps to land; no vmcnt(0) drain in
// the main loop. Per-wave vmcnt is converted to a block-wide guarantee by the
// barrier that follows each counted wait.
// Frag-order LDS (0-conflict). XCD-chunked swizzle (nwg=1568, 8|nwg).
// Writes bf16 logits into TOP half of each d_out row slot + per-(panel,row)
// softmax partials pm/ps transposed (pm[pan*cMQ + row]).
// M=1024, K=512 (16 steps), N=cV fixed.
// ---------------------------------------------------------------------------
__global__ __launch_bounds__(512) void gemm_big(
    const ushort* __restrict__ A, const ushort* __restrict__ Wb,
    const float* __restrict__ bias, ushort* __restrict__ Cb,
    float* __restrict__ pm, float* __restrict__ ps)
{
    __shared__ ushort As[2][8 * 512];     // 8 chunks (128 rows x 32 k)
    __shared__ ushort Bs[2][16 * 512];    // 16 chunks (256 cols x 32 k)
    __shared__ float sm_m[4][128];
    __shared__ float sm_s[4][128];

    const int tid  = threadIdx.x;
    const int lane = tid & 63;
    const int wv   = tid >> 6;     // 0..7
    const int wm   = wv >> 2;      // 0..1 row half
    const int wn   = wv & 3;       // 0..3 col quarter

    // XCD-chunked swizzle over (panel, rowblock); grid (8, 196)
    const int wg  = blockIdx.y * gridDim.x + blockIdx.x;
    const int nwg = gridDim.x * gridDim.y;          // 1568, 8 | nwg
    const int j   = (wg & 7) * (nwg >> 3) + (wg >> 3);
    const int pan = j >> 3;
    const int bm  = (j & 7) * 128;
    const int bn  = pan * 256;

    const int rA = lane & 15;
    const int kA = (lane >> 4) * 8;

    floatx4 acc[4][4] = {};

    // 3 global_load_lds per thread per stage
    auto stage = [&](int bidx, int t) {
        const int k0 = t * 32;
        {   // A: chunk wv
            const int ga = bm + wv * 16 + rA;
            __builtin_amdgcn_global_load_lds(
                (const __attribute__((address_space(1))) void*)(A + (size_t)ga * cD + k0 + kA),
                (__attribute__((address_space(3))) void*)&As[bidx][wv * 512], 16, 0, 0);
        }
        #pragma unroll
        for (int c = 0; c < 2; ++c) {   // B: chunks 2wv, 2wv+1
            const int chunk = wv * 2 + c;
            int gb = bn + chunk * 16 + rA; if (gb >= cV) gb = cV - 1;
            __builtin_amdgcn_global_load_lds(
                (const __attribute__((address_space(1))) void*)(Wb + (size_t)gb * cD + k0 + kA),
                (__attribute__((address_space(3))) void*)&Bs[bidx][chunk * 512], 16, 0, 0);
        }
    };

    // prologue: steps 0 and 1 in flight (6 loads/thread)
    stage(0, 0);
    stage(1, 1);
    asm volatile("s_waitcnt vmcnt(3)" ::: "memory");   // my step-0 loads landed
    __builtin_amdgcn_s_barrier();                      // everyone's landed

    #pragma unroll 1
    for (int t = 0; t < 16; ++t) {
        const int buf = t & 1;
        short8v a[4], b[4];
        #pragma unroll
        for (int mi = 0; mi < 4; ++mi)
            a[mi] = *(const short8v*)&As[buf][(wm * 4 + mi) * 512 + lane * 8];
        #pragma unroll
        for (int ni = 0; ni < 4; ++ni)
            b[ni] = *(const short8v*)&Bs[buf][(wn * 4 + ni) * 512 + lane * 8];
        #pragma unroll
        for (int mi = 0; mi < 4; ++mi)
            #pragma unroll
            for (int ni = 0; ni < 4; ++ni)
                acc[mi][ni] = __builtin_amdgcn_mfma_f32_16x16x32_bf16(
                    a[mi], b[ni], acc[mi][ni], 0, 0, 0);

        __builtin_amdgcn_s_barrier();          // all waves done reading buf

        if (t + 2 < 16) stage(buf, t + 2);     // refill freed buffer (3 loads)
        if (t + 1 < 16) {
            if (t + 2 < 16)
                asm volatile("s_waitcnt vmcnt(3)" ::: "memory");  // t+1 landed (mine)
            else
                asm volatile("s_waitcnt vmcnt(0)" ::: "memory");
            __builtin_amdgcn_s_barrier();      // t+1 landed (everyone)
        }
    }

    // ---- epilogue: bias, per-row stats over 256 cols, bf16 store ----
    const int fr = lane & 15;
    const int g  = lane >> 4;

    float bv[4]; bool val[4];
    #pragma unroll
    for (int ni = 0; ni < 4; ++ni) {
        const int colg = bn + wn * 64 + ni * 16 + fr;
        val[ni] = (colg < cV);
        bv[ni] = val[ni] ? bias[colg] : 0.f;
    }
    #pragma unroll
    for (int mi = 0; mi < 4; ++mi)
        #pragma unroll
        for (int ni = 0; ni < 4; ++ni)
            #pragma unroll
            for (int r = 0; r < 4; ++r)
                acc[mi][ni][r] += bv[ni];

    #pragma unroll
    for (int mi = 0; mi < 4; ++mi) {
        #pragma unroll
        for (int r = 0; r < 4; ++r) {
            float mx = -1e30f;
            #pragma unroll
            for (int ni = 0; ni < 4; ++ni)
                if (val[ni]) mx = fmaxf(mx, acc[mi][ni][r]);
            #pragma unroll
            for (int sw = 1; sw < 16; sw <<= 1)
                mx = fmaxf(mx, __shfl_xor(mx, sw));
            float sm = 0.f;
            #pragma unroll
            for (int ni = 0; ni < 4; ++ni)
                if (val[ni]) sm += __expf(acc[mi][ni][r] - mx);
            #pragma unroll
            for (int sw = 1; sw < 16; sw <<= 1)
                sm += __shfl_xor(sm, sw);
            if (fr == 0) {
                const int rl = wm * 64 + mi * 16 + g * 4 + r;
                sm_m[wn][rl] = mx;
                sm_s[wn][rl] = sm;
            }
        }
    }
    __syncthreads();
    if (tid < 128) {
        float m = sm_m[0][tid], s = sm_s[0][tid];
        #pragma unroll
        for (int i = 1; i < 4; ++i) {
            const float m2 = sm_m[i][tid], s2 = sm_s[i][tid];
            const float nm = fmaxf(m, m2);
            s = s * __expf(m - nm) + s2 * __expf(m2 - nm);
            m = nm;
        }
        const int grow = bm + tid;
        pm[(size_t)pan * cMQ + grow] = m;
        ps[(size_t)pan * cMQ + grow] = s;
    }

    // bf16 logits into top half of output row slot
    #pragma unroll
    for (int mi = 0; mi < 4; ++mi) {
        #pragma unroll
        for (int ni = 0; ni < 4; ++ni) {
            if (!val[ni]) continue;
            const int colg = bn + wn * 64 + ni * 16 + fr;
            #pragma unroll
            for (int r = 0; r < 4; ++r) {
                const int row = bm + wm * 64 + mi * 16 + g * 4 + r;
                Cb[(size_t)row * cCBLD + cTOP + colg] = f2bf(acc[mi][ni][r]);
            }
        }
    }
}

// ---------------------------------------------------------------------------
// combine partials (transposed pm/ps) -> rowadd = log(pgen) - m - log(s).
// Block = 64 rows x 4 panel-stripes; coalesced.
// ---------------------------------------------------------------------------
__global__ __launch_bounds__(256) void combine_kernel(
    const float* __restrict__ pm, const float* __restrict__ ps,
    const float* __restrict__ pgen, float* __restrict__ rowadd)
{
    const int lane = threadIdx.x & 63;
    const int wv   = threadIdx.x >> 6;    // panel stripe 0..3
    const int row  = blockIdx.x * 64 + lane;

    float m = -1e30f, s = 0.f;
    #pragma unroll 2
    for (int i = wv; i < cPAN2; i += 4) {
        const float mi = pm[(size_t)i * cMQ + row];
        const float si = ps[(size_t)i * cMQ + row];
        const float nm = fmaxf(m, mi);
        s = s * __expf(m - nm) + si * __expf(mi - nm);
        m = nm;
    }
    __shared__ float rm[4][64], rs[4][64];
    rm[wv][lane] = m; rs[wv][lane] = s;
    __syncthreads();
    if (wv == 0) {
        m = rm[0][lane]; s = rs[0][lane];
        #pragma unroll
        for (int i = 1; i < 4; ++i) {
            const float m2 = rm[i][lane], s2 = rs[i][lane];
            const float nm = fmaxf(m, m2);
            s = s * __expf(m - nm) + s2 * __expf(m2 - nm);
            m = nm;
        }
        rowadd[row] = __logf(pgen[row]) - m - __logf(s);
    }
}

// ---------------------------------------------------------------------------
// Register-phase in-place transform + fused scatter fixup. One block/row.
// (r11-proven.)
// ---------------------------------------------------------------------------
__global__ __launch_bounds__(512) void transform_reg(
    float* __restrict__ out, const float* __restrict__ rowadd,
    const int* __restrict__ ebev, const float* __restrict__ attn)
{
    const int row = blockIdx.x;
    const int b   = row / cT;
    const int tid = threadIdx.x;
    constexpr float LOGMIN = -20.72326583694641f;   // log(1e-9)
    constexpr int NCHUNK = cV / 8;                  // 6250

    __shared__ int   pos[cS];
    __shared__ float add[cS];
    for (int s = tid; s < cS; s += 512) {
        pos[s] = ebev[b * cS + s];
        add[s] = attn[(size_t)row * cS + s];
    }

    const float a = rowadd[row];
    const ushort* rowu = (const ushort*)out + (size_t)row * cCBLD + cTOP;
    float* rowf = out + (size_t)row * cVEXT;

    ushort4 lo[13], hi[13];
    #pragma unroll
    for (int t = 0; t < 13; ++t) {
        const int cidx = t * 512 + tid;
        if (cidx < NCHUNK) {
            lo[t] = *(const ushort4*)(rowu + (size_t)cidx * 8);
            hi[t] = *(const ushort4*)(rowu + (size_t)cidx * 8 + 4);
        }
    }
    __syncthreads();   // vmcnt drained: all reads of the row are complete

    #pragma unroll
    for (int t = 0; t < 13; ++t) {
        const int cidx = t * 512 + tid;
        if (cidx < NCHUNK) {
            const int jb = cidx * 8;
            float2 o;
            o.x = fmaxf(bf2f(lo[t].x) + a, LOGMIN);
            o.y = fmaxf(bf2f(lo[t].y) + a, LOGMIN);
            *(float2*)(rowf + jb) = o;
            o.x = fmaxf(bf2f(lo[t].z) + a, LOGMIN);
            o.y = fmaxf(bf2f(lo[t].w) + a, LOGMIN);
            *(float2*)(rowf + jb + 2) = o;
            o.x = fmaxf(bf2f(hi[t].x) + a, LOGMIN);
            o.y = fmaxf(bf2f(hi[t].y) + a, LOGMIN);
            *(float2*)(rowf + jb + 4) = o;
            o.x = fmaxf(bf2f(hi[t].z) + a, LOGMIN);
            o.y = fmaxf(bf2f(hi[t].w) + a, LOGMIN);
            *(float2*)(rowf + jb + 6) = o;
        }
    }
    if (tid < (cVEXT - cV) / 2) {   // LOGMIN tail [50000, 50050)
        float2 z; z.x = LOGMIN; z.y = LOGMIN;
        *(float2*)(rowf + cV + 2 * tid) = z;
    }
    __syncthreads();

    // scatter fixup
    for (int s = tid; s < cS; s += 512) {
        const int p = pos[s];
        bool leader = true;
        for (int s2 = 0; s2 < s; ++s2)
            if (pos[s2] == p) { leader = false; break; }
        if (!leader) continue;
        float sum = add[s];
        for (int s2 = s + 1; s2 < cS; ++s2)
            if (pos[s2] == p) sum += add[s2];
        const float base = __expf(rowf[p]);   // clamped; error << threshold
        rowf[p] = __logf(fmaxf(base + sum, 1e-9f));
    }
}

// ---------------------------------------------------------------------------
// p_gen = sigmoid(x . pgen_w + pgen_b)
// ---------------------------------------------------------------------------
__global__ __launch_bounds__(64) void pgen_kernel(
    const float* __restrict__ x, const float* __restrict__ w,
    const float* __restrict__ b, float* __restrict__ pgen)
{
    const int row = blockIdx.x;
    const int lane = threadIdx.x;
    const float* xr = x + (size_t)row * cD;
    float s = 0.f;
    for (int i = lane; i < cD; i += 64) s += xr[i] * w[i];
    #pragma unroll
    for (int off = 32; off; off >>= 1) s += __shfl_down(s, off);
    if (lane == 0) pgen[row] = 1.f / (1.f + __expf(-(s + b[0])));
}

// ---------------------------------------------------------------------------
// attention distribution (scaled by 1-pgen)
// ---------------------------------------------------------------------------
__global__ __launch_bounds__(256) void attn_kernel(
    const float* __restrict__ q, const float* __restrict__ k,
    const int* __restrict__ src_mask, const float* __restrict__ pgen,
    float* __restrict__ attn)
{
    constexpr float scale = 0.04419417382415922f;  // 1/sqrt(512)
    const int row = blockIdx.x;      // b*T + t
    const int b = row / cT;
    const int tid = threadIdx.x;

    __shared__ __align__(16) float qs[cD];
    __shared__ float sc[cS];
    __shared__ float red[4];

    for (int i = tid; i < cD; i += 256) qs[i] = q[(size_t)row * cD + i];
    __syncthreads();

    for (int s = tid; s < cS; s += 256) {
        const float* kr = k + ((size_t)b * cS + s) * cD;
        float dot = 0.f;
        #pragma unroll 4
        for (int i = 0; i < cD; i += 4) {
            float4 kv = *(const float4*)(kr + i);
            float4 qv = *(const float4*)(qs + i);
            dot += qv.x * kv.x + qv.y * kv.y + qv.z * kv.z + qv.w * kv.w;
        }
        float v = dot * scale;
        if (src_mask[b * cS + s] == 0) v = -1e9f;
        sc[s] = v;
    }
    __syncthreads();

    float m = -3.4e38f;
    for (int s = tid; s < cS; s += 256) m = fmaxf(m, sc[s]);
    #pragma unroll
    for (int off = 32; off; off >>= 1) m = fmaxf(m, __shfl_down(m, off));
    if ((tid & 63) == 0) red[tid >> 6] = m;
    __syncthreads();
    m = fmaxf(fmaxf(red[0], red[1]), fmaxf(red[2], red[3]));
    __syncthreads();

    float sum = 0.f;
    for (int s = tid; s < cS; s += 256) {
        float e = __expf(sc[s] - m);
        sc[s] = e;
        sum += e;
    }
    #pragma unroll
    for (int off = 32; off; off >>= 1) sum += __shfl_down(sum, off);
    if ((tid & 63) == 0) red[tid >> 6] = sum;
    __syncthreads();
    sum = red[0] + red[1] + red[2] + red[3];

    const float w = (1.f - pgen[row]) / sum;
    for (int s = tid; s < cS; s += 256)
        attn[(size_t)row * cS + s] = sc[s] * w;
}

extern "C" void kernel_launch(void* const* d_in, const int* in_sizes, int n_in,
                              void* d_out, int out_size, void* d_ws, size_t ws_size,
                              hipStream_t stream)
{
    const float* x      = (const float*)d_in[0];   // (B,T,D)
    const float* enc    = (const float*)d_in[1];   // (B,S,D)
    const int*   mask   = (const int*)d_in[2];     // (B,1,S)
    const int*   ebev   = (const int*)d_in[3];     // (B,S)
    const float* fc_w   = (const float*)d_in[5];   // (V,D)
    const float* fc_b   = (const float*)d_in[6];   // (V,)
    const float* pgen_w = (const float*)d_in[7];   // (1,D)
    const float* pgen_b = (const float*)d_in[8];   // (1,)
    const float* wq     = (const float*)d_in[9];   // (D,D)
    const float* bq     = (const float*)d_in[10];  // (D,)
    const float* wk     = (const float*)d_in[11];  // (D,D)
    const float* bk     = (const float*)d_in[12];  // (D,)
    float* out = (float*)d_out;

    // workspace layout (~65 MB; proven to fit)
    float* ws     = (float*)d_ws;
    float* q      = ws;                                   // 1024*512
    float* kbuf   = q + (size_t)cB * cT * cD;             // 1600*512
    float* pgen   = kbuf + (size_t)cB * cS * cD;          // 1024
    float* attn   = pgen + cB * cT;                       // 1024*400
    float* pm     = attn + (size_t)cB * cT * cS;          // 196*1024 (transposed)
    float* ps     = pm + (size_t)cPAN2 * cMQ;             // 196*1024
    float* rowadd = ps + (size_t)cPAN2 * cMQ;             // 1024
    ushort* xb    = (ushort*)(rowadd + cMQ);
    ushort* encb  = xb + (size_t)cB * cT * cD;
    ushort* wqb   = encb + (size_t)cB * cS * cD;
    ushort* wkb   = wqb + (size_t)cD * cD;
    ushort* wb    = wkb + (size_t)cD * cD;                // V*D bf16 (51 MB)

    const dim3 blk(256);
    const int MQ = cMQ;        // 1024
    const int MK = cB * cS;    // 1600

    // casts
    cast_kernel<<<dim3(512), blk, 0, stream>>>(x, xb, (cB * cT * cD) / 4);
    cast_kernel<<<dim3(512), blk, 0, stream>>>(enc, encb, (cB * cS * cD) / 4);
    cast_kernel<<<dim3(256), blk, 0, stream>>>(wq, wqb, (cD * cD) / 4);
    cast_kernel<<<dim3(256), blk, 0, stream>>>(wk, wkb, (cD * cD) / 4);
    cast_kernel<<<dim3(2048), blk, 0, stream>>>(fc_w, wb, (cV * cD) / 4);

    // projections (bf16 MFMA, fp32 out)
    gemm_proj<<<dim3(MQ / 128, cD / 128), blk, 0, stream>>>(
        xb, wqb, bq, q, MQ, cD, cD, cD);
    gemm_proj<<<dim3((MK + 127) / 128, cD / 128), blk, 0, stream>>>(
        encb, wkb, bk, kbuf, MK, cD, cD, cD);
    pgen_kernel<<<dim3(MQ), dim3(64), 0, stream>>>(x, pgen_w, pgen_b, pgen);

    // attention distribution
    attn_kernel<<<dim3(MQ), blk, 0, stream>>>(q, kbuf, mask, pgen, attn);

    // big logits GEMM: bf16 logits into row-slot top half + softmax partials
    gemm_big<<<dim3(8, cPAN2), dim3(512), 0, stream>>>(
        xb, wb, fc_b, (ushort*)out, pm, ps);

    // combine partials -> rowadd
    combine_kernel<<<dim3(MQ / 64), blk, 0, stream>>>(pm, ps, pgen, rowadd);

    // register-phase in-place expand + fused scatter fixup
    transform_reg<<<dim3(MQ), dim3(512), 0, stream>>>(out, rowadd, ebev, attn);
}

// Round 13
// 414.827 us; speedup vs baseline: 1.0253x; 1.0253x over previous
//
#include <hip/hip_runtime.h>
#include <hip/hip_bf16.h>
#include <math.h>

// Problem constants
constexpr int cB = 4, cT = 256, cS = 400, cD = 512, cV = 50000, cNX = 50;
constexpr int cVEXT = cV + cNX;           // 50050
constexpr int cPAN  = (cV + 127) / 128;   // 391 col panels (128-wide)
constexpr int cCBLD = cVEXT * 2;          // ushort stride of one fp32 out row
constexpr int cTOP  = 50100;              // ushort offset of bf16 logits in-slot
constexpr int cMQ   = cB * cT;            // 1024

typedef __attribute__((ext_vector_type(8))) short short8v;   // 8 bf16
typedef __attribute__((ext_vector_type(4))) float floatx4;

__device__ inline ushort f2bf(float f) {
    union { float f; unsigned u; } v; v.f = f;
    unsigned r = (v.u + 0x7FFFu + ((v.u >> 16) & 1u)) >> 16;
    return (ushort)r;
}
__device__ inline float bf2f(ushort u) {
    union { unsigned u; float f; } v; v.u = ((unsigned)u) << 16;
    return v.f;
}

// ---------------------------------------------------------------------------
// fp32 -> bf16 cast
// ---------------------------------------------------------------------------
__global__ __launch_bounds__(256) void cast_kernel(
    const float* __restrict__ src, ushort* __restrict__ dst, int n4)
{
    const int stride = gridDim.x * 256;
    for (int i = blockIdx.x * 256 + threadIdx.x; i < n4; i += stride) {
        float4 v = *(const float4*)(src + (size_t)i * 4);
        ushort4 o;
        o.x = f2bf(v.x); o.y = f2bf(v.y); o.z = f2bf(v.z); o.w = f2bf(v.w);
        *(ushort4*)(dst + (size_t)i * 4) = o;
    }
}

// ---------------------------------------------------------------------------
// Small bf16 MFMA GEMM (projections): 128x128 tile, BK=32, 4 waves, frag-order
// LDS, fp32 C + bias. Plain block mapping. (r11-proven, small cost.)
// ---------------------------------------------------------------------------
__global__ __launch_bounds__(256) void gemm_proj(
    const ushort* __restrict__ A, const ushort* __restrict__ Wb,
    const float* __restrict__ bias, float* __restrict__ Cf,
    int M, int N, int K, int ldc)
{
    __shared__ ushort As[2][128 * 32];
    __shared__ ushort Bs[2][128 * 32];

    const int tid  = threadIdx.x;
    const int lane = tid & 63;
    const int wv   = tid >> 6;
    const int wm   = wv >> 1;
    const int wn   = wv & 1;
    const int bm   = blockIdx.x * 128;
    const int bn   = blockIdx.y * 128;

    const int rA = lane & 15;
    const int kA = (lane >> 4) * 8;
    const int nt = K >> 5;

    floatx4 acc[4][4] = {};

    auto stage = [&](int bidx, int t) {
        const int k0 = t * 32;
        #pragma unroll
        for (int c = 0; c < 2; ++c) {
            const int chunk = wv * 2 + c;
            int ga = bm + chunk * 16 + rA; if (ga >= M) ga = M - 1;
            __builtin_amdgcn_global_load_lds(
                (const __attribute__((address_space(1))) void*)(A + (size_t)ga * K + k0 + kA),
                (__attribute__((address_space(3))) void*)&As[bidx][chunk * 512], 16, 0, 0);
            int gb = bn + chunk * 16 + rA; if (gb >= N) gb = N - 1;
            __builtin_amdgcn_global_load_lds(
                (const __attribute__((address_space(1))) void*)(Wb + (size_t)gb * K + k0 + kA),
                (__attribute__((address_space(3))) void*)&Bs[bidx][chunk * 512], 16, 0, 0);
        }
    };

    stage(0, 0);
    __syncthreads();

    int buf = 0;
    for (int t = 0; t < nt; ++t) {
        if (t + 1 < nt) stage(buf ^ 1, t + 1);
        short8v a[4], b[4];
        #pragma unroll
        for (int mi = 0; mi < 4; ++mi)
            a[mi] = *(const short8v*)&As[buf][(wm * 4 + mi) * 512 + lane * 8];
        #pragma unroll
        for (int ni = 0; ni < 4; ++ni)
            b[ni] = *(const short8v*)&Bs[buf][(wn * 4 + ni) * 512 + lane * 8];
        #pragma unroll
        for (int mi = 0; mi < 4; ++mi)
            #pragma unroll
            for (int ni = 0; ni < 4; ++ni)
                acc[mi][ni] = __builtin_amdgcn_mfma_f32_16x16x32_bf16(
                    a[mi], b[ni], acc[mi][ni], 0, 0, 0);
        __syncthreads();
        buf ^= 1;
    }

    const int fr = lane & 15;
    const int g  = lane >> 4;
    #pragma unroll
    for (int mi = 0; mi < 4; ++mi) {
        #pragma unroll
        for (int ni = 0; ni < 4; ++ni) {
            const int colg = bn + wn * 64 + ni * 16 + fr;
            if (colg >= N) continue;
            const float bv = bias[colg];
            #pragma unroll
            for (int r = 0; r < 4; ++r) {
                const int row = bm + wm * 64 + mi * 16 + g * 4 + r;
                if (row < M) Cf[(size_t)row * ldc + colg] = acc[mi][ni][r] + bv;
            }
        }
    }
}

// ---------------------------------------------------------------------------
// Big logits GEMM: EXACT r7 structure (best-measured: 144 us). 128x128 tile,
// BK=32, 4 waves (2x2), [row][k] LDS layout, A+B double-buffered, one
// __syncthreads per K-step, stage(t+1) issued before compute(t).
// XCD-chunked swizzle over (panel=391, rowblock=8), nwg=3128 (8|nwg).
// Writes bf16 logits into TOP half of each d_out row slot (ushort offset
// cTOP, stride cCBLD) + per-(panel,row) softmax partials transposed
// (pm[pan*cMQ + row]). M=1024, K=512, N=cV.
// ---------------------------------------------------------------------------
__global__ __launch_bounds__(256) void gemm_big(
    const ushort* __restrict__ A, const ushort* __restrict__ Wb,
    const float* __restrict__ bias, ushort* __restrict__ Cb,
    float* __restrict__ pm, float* __restrict__ ps)
{
    __shared__ ushort As[2][128 * 32];
    __shared__ ushort Bs[2][128 * 32];
    __shared__ float sm_m[2][128];
    __shared__ float sm_s[2][128];

    const int tid  = threadIdx.x;
    const int lane = tid & 63;
    const int wv   = tid >> 6;
    const int wm   = wv >> 1;
    const int wn   = wv & 1;

    // XCD-chunked swizzle: grid (8, 391), nwg = 3128, 8 | nwg
    const int wg  = blockIdx.y * gridDim.x + blockIdx.x;
    const int nwg = gridDim.x * gridDim.y;
    const int j   = (wg & 7) * (nwg >> 3) + (wg >> 3);
    const int pan = j >> 3;
    const int bm  = (j & 7) * 128;
    const int bn  = pan * 128;

    const int srow = lane >> 2;        // 0..15
    const int sk   = (lane & 3) * 8;   // bf16 elems

    floatx4 acc[4][4] = {};

    auto stage = [&](int bidx, int t) {
        const int k0 = t * 32;
        #pragma unroll
        for (int c = 0; c < 2; ++c) {
            const int lr = wv * 32 + c * 16;
            const int ga = bm + lr + srow;                 // M=1024, always valid
            __builtin_amdgcn_global_load_lds(
                (const __attribute__((address_space(1))) void*)(A + (size_t)ga * cD + k0 + sk),
                (__attribute__((address_space(3))) void*)&As[bidx][lr * 32], 16, 0, 0);
        }
        #pragma unroll
        for (int c = 0; c < 2; ++c) {
            const int lr = wv * 32 + c * 16;
            int gb = bn + lr + srow; if (gb >= cV) gb = cV - 1;
            __builtin_amdgcn_global_load_lds(
                (const __attribute__((address_space(1))) void*)(Wb + (size_t)gb * cD + k0 + sk),
                (__attribute__((address_space(3))) void*)&Bs[bidx][lr * 32], 16, 0, 0);
        }
    };

    stage(0, 0);
    __syncthreads();

    const int fr = lane & 15;
    const int g  = lane >> 4;
    int buf = 0;

    #pragma unroll 1
    for (int t = 0; t < 16; ++t) {
        if (t + 1 < 16) stage(buf ^ 1, t + 1);
        short8v a[4], b[4];
        #pragma unroll
        for (int mi = 0; mi < 4; ++mi)
            a[mi] = *(const short8v*)&As[buf][(wm * 64 + mi * 16 + fr) * 32 + g * 8];
        #pragma unroll
        for (int ni = 0; ni < 4; ++ni)
            b[ni] = *(const short8v*)&Bs[buf][(wn * 64 + ni * 16 + fr) * 32 + g * 8];
        #pragma unroll
        for (int mi = 0; mi < 4; ++mi)
            #pragma unroll
            for (int ni = 0; ni < 4; ++ni)
                acc[mi][ni] = __builtin_amdgcn_mfma_f32_16x16x32_bf16(
                    a[mi], b[ni], acc[mi][ni], 0, 0, 0);
        __syncthreads();
        buf ^= 1;
    }

    // ---- epilogue: bias, per-row stats, bf16 top-half store ----
    float bv[4]; bool val[4];
    #pragma unroll
    for (int ni = 0; ni < 4; ++ni) {
        const int colg = bn + wn * 64 + ni * 16 + fr;
        val[ni] = (colg < cV);
        bv[ni] = val[ni] ? bias[colg] : 0.f;
    }
    #pragma unroll
    for (int mi = 0; mi < 4; ++mi)
        #pragma unroll
        for (int ni = 0; ni < 4; ++ni)
            #pragma unroll
            for (int r = 0; r < 4; ++r)
                acc[mi][ni][r] += bv[ni];

    #pragma unroll
    for (int mi = 0; mi < 4; ++mi) {
        #pragma unroll
        for (int r = 0; r < 4; ++r) {
            float mx = -1e30f;
            #pragma unroll
            for (int ni = 0; ni < 4; ++ni)
                if (val[ni]) mx = fmaxf(mx, acc[mi][ni][r]);
            #pragma unroll
            for (int sw = 1; sw < 16; sw <<= 1)
                mx = fmaxf(mx, __shfl_xor(mx, sw));
            float sm = 0.f;
            #pragma unroll
            for (int ni = 0; ni < 4; ++ni)
                if (val[ni]) sm += __expf(acc[mi][ni][r] - mx);
            #pragma unroll
            for (int sw = 1; sw < 16; sw <<= 1)
                sm += __shfl_xor(sm, sw);
            if (fr == 0) {
                const int rl = wm * 64 + mi * 16 + g * 4 + r;
                sm_m[wn][rl] = mx;
                sm_s[wn][rl] = sm;
            }
        }
    }
    __syncthreads();
    if (tid < 128) {
        const float m0 = sm_m[0][tid], m1 = sm_m[1][tid];
        const float s0 = sm_s[0][tid], s1 = sm_s[1][tid];
        const float mm = fmaxf(m0, m1);
        const float ss = s0 * __expf(m0 - mm) + s1 * __expf(m1 - mm);
        const int grow = bm + tid;
        pm[(size_t)pan * cMQ + grow] = mm;   // transposed: contiguous per block
        ps[(size_t)pan * cMQ + grow] = ss;
    }

    // bf16 logits into top half of output row slot
    #pragma unroll
    for (int mi = 0; mi < 4; ++mi) {
        #pragma unroll
        for (int ni = 0; ni < 4; ++ni) {
            if (!val[ni]) continue;
            const int colg = bn + wn * 64 + ni * 16 + fr;
            #pragma unroll
            for (int r = 0; r < 4; ++r) {
                const int row = bm + wm * 64 + mi * 16 + g * 4 + r;
                Cb[(size_t)row * cCBLD + cTOP + colg] = f2bf(acc[mi][ni][r]);
            }
        }
    }
}

// ---------------------------------------------------------------------------
// combine partials (transposed pm/ps, 391 panels) -> rowadd.
// Block = 64 rows x 4 panel-stripes; coalesced.
// ---------------------------------------------------------------------------
__global__ __launch_bounds__(256) void combine_kernel(
    const float* __restrict__ pm, const float* __restrict__ ps,
    const float* __restrict__ pgen, float* __restrict__ rowadd)
{
    const int lane = threadIdx.x & 63;
    const int wv   = threadIdx.x >> 6;    // panel stripe 0..3
    const int row  = blockIdx.x * 64 + lane;

    float m = -1e30f, s = 0.f;
    #pragma unroll 2
    for (int i = wv; i < cPAN; i += 4) {
        const float mi = pm[(size_t)i * cMQ + row];
        const float si = ps[(size_t)i * cMQ + row];
        const float nm = fmaxf(m, mi);
        s = s * __expf(m - nm) + si * __expf(mi - nm);
        m = nm;
    }
    __shared__ float rm[4][64], rs[4][64];
    rm[wv][lane] = m; rs[wv][lane] = s;
    __syncthreads();
    if (wv == 0) {
        m = rm[0][lane]; s = rs[0][lane];
        #pragma unroll
        for (int i = 1; i < 4; ++i) {
            const float m2 = rm[i][lane], s2 = rs[i][lane];
            const float nm = fmaxf(m, m2);
            s = s * __expf(m - nm) + s2 * __expf(m2 - nm);
            m = nm;
        }
        rowadd[row] = __logf(pgen[row]) - m - __logf(s);
    }
}

// ---------------------------------------------------------------------------
// 4-batch register-phase in-place transform + fused scatter fixup.
// One block (512) per row. Batches over slot t (chunk = t*512+tid, 8 bf16
// per chunk): boundaries {0,4,7,10,13}. Safety: writes of batches <= b end
// at byte 16384*L, reads of batch b+1 start at 100200+8192*L (L = boundary);
// 16384L <= 100200+8192L holds for L in {4,7,10}. One barrier per batch
// between its loads (all complete: vmcnt drained by s_barrier) and stores.
// ~16 staging VGPR -> 32 waves/CU -> 4 blocks/CU (single generation).
// ---------------------------------------------------------------------------
__global__ __launch_bounds__(512) void transform_reg(
    float* __restrict__ out, const float* __restrict__ rowadd,
    const int* __restrict__ ebev, const float* __restrict__ attn)
{
    const int row = blockIdx.x;
    const int b   = row / cT;
    const int tid = threadIdx.x;
    constexpr float LOGMIN = -20.72326583694641f;   // log(1e-9)
    constexpr int NCHUNK = cV / 8;                  // 6250

    __shared__ int   pos[cS];
    __shared__ float add[cS];
    for (int s = tid; s < cS; s += 512) {
        pos[s] = ebev[b * cS + s];
        add[s] = attn[(size_t)row * cS + s];
    }

    const float a = rowadd[row];
    const ushort* rowu = (const ushort*)out + (size_t)row * cCBLD + cTOP;
    float* rowf = out + (size_t)row * cVEXT;

    constexpr int BLO[5] = {0, 4, 7, 10, 13};
    #pragma unroll
    for (int bb = 0; bb < 4; ++bb) {
        ushort4 lo[4], hi[4];
        #pragma unroll
        for (int s = 0; s < 4; ++s) {
            const int t = BLO[bb] + s;
            if (t < BLO[bb + 1]) {
                const int cidx = t * 512 + tid;
                if (cidx < NCHUNK) {
                    lo[s] = *(const ushort4*)(rowu + (size_t)cidx * 8);
                    hi[s] = *(const ushort4*)(rowu + (size_t)cidx * 8 + 4);
                }
            }
        }
        __syncthreads();   // all batch reads landed before any batch write
        #pragma unroll
        for (int s = 0; s < 4; ++s) {
            const int t = BLO[bb] + s;
            if (t < BLO[bb + 1]) {
                const int cidx = t * 512 + tid;
                if (cidx < NCHUNK) {
                    const int jb = cidx * 8;
                    float2 o;
                    o.x = fmaxf(bf2f(lo[s].x) + a, LOGMIN);
                    o.y = fmaxf(bf2f(lo[s].y) + a, LOGMIN);
                    *(float2*)(rowf + jb) = o;
                    o.x = fmaxf(bf2f(lo[s].z) + a, LOGMIN);
                    o.y = fmaxf(bf2f(lo[s].w) + a, LOGMIN);
                    *(float2*)(rowf + jb + 2) = o;
                    o.x = fmaxf(bf2f(hi[s].x) + a, LOGMIN);
                    o.y = fmaxf(bf2f(hi[s].y) + a, LOGMIN);
                    *(float2*)(rowf + jb + 4) = o;
                    o.x = fmaxf(bf2f(hi[s].z) + a, LOGMIN);
                    o.y = fmaxf(bf2f(hi[s].w) + a, LOGMIN);
                    *(float2*)(rowf + jb + 6) = o;
                }
            }
        }
    }
    // LOGMIN tail [50000, 50050): written after the last batch's load barrier
    if (tid < (cVEXT - cV) / 2) {
        float2 z; z.x = LOGMIN; z.y = LOGMIN;
        *(float2*)(rowf + cV + 2 * tid) = z;
    }
    __syncthreads();

    // scatter fixup
    for (int s = tid; s < cS; s += 512) {
        const int p = pos[s];
        bool leader = true;
        for (int s2 = 0; s2 < s; ++s2)
            if (pos[s2] == p) { leader = false; break; }
        if (!leader) continue;
        float sum = add[s];
        for (int s2 = s + 1; s2 < cS; ++s2)
            if (pos[s2] == p) sum += add[s2];
        const float base = __expf(rowf[p]);   // clamped; error << threshold
        rowf[p] = __logf(fmaxf(base + sum, 1e-9f));
    }
}

// ---------------------------------------------------------------------------
// p_gen = sigmoid(x . pgen_w + pgen_b)
// ---------------------------------------------------------------------------
__global__ __launch_bounds__(64) void pgen_kernel(
    const float* __restrict__ x, const float* __restrict__ w,
    const float* __restrict__ b, float* __restrict__ pgen)
{
    const int row = blockIdx.x;
    const int lane = threadIdx.x;
    const float* xr = x + (size_t)row * cD;
    float s = 0.f;
    for (int i = lane; i < cD; i += 64) s += xr[i] * w[i];
    #pragma unroll
    for (int off = 32; off; off >>= 1) s += __shfl_down(s, off);
    if (lane == 0) pgen[row] = 1.f / (1.f + __expf(-(s + b[0])));
}

// ---------------------------------------------------------------------------
// attention distribution (scaled by 1-pgen)
// ---------------------------------------------------------------------------
__global__ __launch_bounds__(256) void attn_kernel(
    const float* __restrict__ q, const float* __restrict__ k,
    const int* __restrict__ src_mask, const float* __restrict__ pgen,
    float* __restrict__ attn)
{
    constexpr float scale = 0.04419417382415922f;  // 1/sqrt(512)
    const int row = blockIdx.x;      // b*T + t
    const int b = row / cT;
    const int tid = threadIdx.x;

    __shared__ __align__(16) float qs[cD];
    __shared__ float sc[cS];
    __shared__ float red[4];

    for (int i = tid; i < cD; i += 256) qs[i] = q[(size_t)row * cD + i];
    __syncthreads();

    for (int s = tid; s < cS; s += 256) {
        const float* kr = k + ((size_t)b * cS + s) * cD;
        float dot = 0.f;
        #pragma unroll 4
        for (int i = 0; i < cD; i += 4) {
            float4 kv = *(const float4*)(kr + i);
            float4 qv = *(const float4*)(qs + i);
            dot += qv.x * kv.x + qv.y * kv.y + qv.z * kv.z + qv.w * kv.w;
        }
        float v = dot * scale;
        if (src_mask[b * cS + s] == 0) v = -1e9f;
        sc[s] = v;
    }
    __syncthreads();

    float m = -3.4e38f;
    for (int s = tid; s < cS; s += 256) m = fmaxf(m, sc[s]);
    #pragma unroll
    for (int off = 32; off; off >>= 1) m = fmaxf(m, __shfl_down(m, off));
    if ((tid & 63) == 0) red[tid >> 6] = m;
    __syncthreads();
    m = fmaxf(fmaxf(red[0], red[1]), fmaxf(red[2], red[3]));
    __syncthreads();

    float sum = 0.f;
    for (int s = tid; s < cS; s += 256) {
        float e = __expf(sc[s] - m);
        sc[s] = e;
        sum += e;
    }
    #pragma unroll
    for (int off = 32; off; off >>= 1) sum += __shfl_down(sum, off);
    if ((tid & 63) == 0) red[tid >> 6] = sum;
    __syncthreads();
    sum = red[0] + red[1] + red[2] + red[3];

    const float w = (1.f - pgen[row]) / sum;
    for (int s = tid; s < cS; s += 256)
        attn[(size_t)row * cS + s] = sc[s] * w;
}

extern "C" void kernel_launch(void* const* d_in, const int* in_sizes, int n_in,
                              void* d_out, int out_size, void* d_ws, size_t ws_size,
                              hipStream_t stream)
{
    const float* x      = (const float*)d_in[0];   // (B,T,D)
    const float* enc    = (const float*)d_in[1];   // (B,S,D)
    const int*   mask   = (const int*)d_in[2];     // (B,1,S)
    const int*   ebev   = (const int*)d_in[3];     // (B,S)
    const float* fc_w   = (const float*)d_in[5];   // (V,D)
    const float* fc_b   = (const float*)d_in[6];   // (V,)
    const float* pgen_w = (const float*)d_in[7];   // (1,D)
    const float* pgen_b = (const float*)d_in[8];   // (1,)
    const float* wq     = (const float*)d_in[9];   // (D,D)
    const float* bq     = (const float*)d_in[10];  // (D,)
    const float* wk     = (const float*)d_in[11];  // (D,D)
    const float* bk     = (const float*)d_in[12];  // (D,)
    float* out = (float*)d_out;

    // workspace layout (~68 MB; fits as in prior rounds)
    float* ws     = (float*)d_ws;
    float* q      = ws;                                   // 1024*512
    float* kbuf   = q + (size_t)cB * cT * cD;             // 1600*512
    float* pgen   = kbuf + (size_t)cB * cS * cD;          // 1024
    float* attn   = pgen + cB * cT;                       // 1024*400
    float* pm     = attn + (size_t)cB * cT * cS;          // 391*1024 (transposed)
    float* ps     = pm + (size_t)cPAN * cMQ;              // 391*1024
    float* rowadd = ps + (size_t)cPAN * cMQ;              // 1024
    ushort* xb    = (ushort*)(rowadd + cMQ);
    ushort* encb  = xb + (size_t)cB * cT * cD;
    ushort* wqb   = encb + (size_t)cB * cS * cD;
    ushort* wkb   = wqb + (size_t)cD * cD;
    ushort* wb    = wkb + (size_t)cD * cD;                // V*D bf16 (51 MB)

    const dim3 blk(256);
    const int MQ = cMQ;        // 1024
    const int MK = cB * cS;    // 1600

    // casts
    cast_kernel<<<dim3(512), blk, 0, stream>>>(x, xb, (cB * cT * cD) / 4);
    cast_kernel<<<dim3(512), blk, 0, stream>>>(enc, encb, (cB * cS * cD) / 4);
    cast_kernel<<<dim3(256), blk, 0, stream>>>(wq, wqb, (cD * cD) / 4);
    cast_kernel<<<dim3(256), blk, 0, stream>>>(wk, wkb, (cD * cD) / 4);
    cast_kernel<<<dim3(2048), blk, 0, stream>>>(fc_w, wb, (cV * cD) / 4);

    // projections (bf16 MFMA, fp32 out)
    gemm_proj<<<dim3(MQ / 128, cD / 128), blk, 0, stream>>>(
        xb, wqb, bq, q, MQ, cD, cD, cD);
    gemm_proj<<<dim3((MK + 127) / 128, cD / 128), blk, 0, stream>>>(
        encb, wkb, bk, kbuf, MK, cD, cD, cD);
    pgen_kernel<<<dim3(MQ), dim3(64), 0, stream>>>(x, pgen_w, pgen_b, pgen);

    // attention distribution
    attn_kernel<<<dim3(MQ), blk, 0, stream>>>(q, kbuf, mask, pgen, attn);

    // big logits GEMM (r7 structure): bf16 logits into row-slot top half
    gemm_big<<<dim3(8, cPAN), blk, 0, stream>>>(
        xb, wb, fc_b, (ushort*)out, pm, ps);

    // combine partials -> rowadd
    combine_kernel<<<dim3(MQ / 64), blk, 0, stream>>>(pm, ps, pgen, rowadd);

    // 4-batch register-phase in-place expand + fused scatter fixup
    transform_reg<<<dim3(MQ), dim3(512), 0, stream>>>(out, rowadd, ebev, attn);
}